// Round 6
// baseline (340.290 us; speedup 1.0000x reference)
//
#include <hip/hip_runtime.h>
#include <hip/hip_bf16.h>
#include <math.h>

// Problem constants
#define Bn 16
#define Cc 256
#define Hh 64
#define Ww 64
#define HW 4096
#define C2 512
#define Pp 65536          // Bn*HW
#define EPSc 1e-5f

typedef __attribute__((ext_vector_type(8))) short short8;
typedef __attribute__((ext_vector_type(4))) float floatx4;

// ---------------------------------------------------------------------------
// Kernel 0 (merged): blocks 0..511 combine weights (split-K);
// blocks 512.. convert w_pw/w_final to bf16 and pad w_dw.
// ---------------------------------------------------------------------------
__device__ inline void cvt4(const float* __restrict__ a,
                            __hip_bfloat16* __restrict__ o, int q) {
    float4 v = *(const float4*)&a[q * 4];
    __hip_bfloat16 r[4];
    r[0] = __float2bfloat16(v.x);
    r[1] = __float2bfloat16(v.y);
    r[2] = __float2bfloat16(v.z);
    r[3] = __float2bfloat16(v.w);
    *(uint2*)&o[q * 4] = *(const uint2*)r;
}

__global__ __launch_bounds__(512)
void weights_all(const float* __restrict__ w_expand,
                 const float* __restrict__ freq_real,
                 const float* __restrict__ w_poly,
                 const float* __restrict__ gamma,
                 const float* __restrict__ beta,
                 const float* __restrict__ w_pw,
                 const float* __restrict__ w_final,
                 const float* __restrict__ w_dw,
                 __hip_bfloat16* __restrict__ W1g_b,
                 float* __restrict__ bias1,
                 float* __restrict__ wsum,
                 __hip_bfloat16* __restrict__ w_pw_b,
                 __hip_bfloat16* __restrict__ w_final_b,
                 float* __restrict__ w_dw_p) {
    int tid = threadIdx.x;
    if (blockIdx.x >= 512) {
        int i = (blockIdx.x - 512) * 512 + tid;
        if (i < 65536) {
            cvt4(w_pw, w_pw_b, i);
        } else if (i < 98304) {
            cvt4(w_final, w_final_b, i - 65536);
        } else {
            int j = i - 98304;
            if (j < C2 * 12) {
                int k = j / 12, l = j - k * 12;
                w_dw_p[j] = (l < 9) ? w_dw[k * 9 + l] : 0.f;
            }
        }
        return;
    }
    int o = blockIdx.x;
    int c = tid & 255;
    int kh = tid >> 8;           // 0/1: K-half
    float acc = 0.f;
    const float* wp = w_poly + (size_t)o * C2 + kh * 256;
    const float* fr = freq_real + kh * 256;
    const float* we = w_expand + (size_t)(kh * 256) * Cc + c;
    for (int m = 0; m < 256; ++m) {
        acc += wp[m] * fr[m] * we[(size_t)m * Cc];
    }
    __shared__ float part[512];
    __shared__ float redB[256];
    __shared__ float redG[256];
    part[tid] = acc;
    __syncthreads();
    if (tid < 256) {
        float a = part[tid] + part[tid + 256];
        float wg = a * gamma[c];
        W1g_b[(size_t)o * Cc + c] = __float2bfloat16(wg);
        redB[c] = a * beta[c];
        redG[c] = wg;
    }
    __syncthreads();
    for (int s = 128; s > 0; s >>= 1) {
        if (tid < s) { redB[tid] += redB[tid + s]; redG[tid] += redG[tid + s]; }
        __syncthreads();
    }
    if (tid == 0) { bias1[o] = redB[0]; wsum[o] = redG[0]; }
}

// ---------------------------------------------------------------------------
// Kernel 1: gemm1h — fused LN-stats + GEMM1, fine-grained blocks.
// 4096 blocks x 256 thr (4 waves): block = (b, h, pos-half 32, outch-half 256).
// Stages A = f[b, :, 32 pos] (fp32->bf16) into LDS + LN partials; barrier-free
// K-loop (B = W1g_b depth-2 reg prefetch); epilogue affine -> LDS bounce ->
// 64B-sector coalesced f5 stores. XCD swizzle keeps sibling blocks (sharing
// staged f rows / f5 lines) on the same L2.
// ---------------------------------------------------------------------------
#define XPAD 264   // LDS A-row pitch in bf16

__global__ __launch_bounds__(256, 4)
void gemm1h(const float* __restrict__ f,
            const __hip_bfloat16* __restrict__ W1g_b,
            const float* __restrict__ bias1,
            const float* __restrict__ wsum,
            __hip_bfloat16* __restrict__ f5) {
    // carve: As 16896 | redS 4224 | redQ 4224 | red2S 1024 | red2Q 1024
    //      | muS 128 | rsS 128  = 27,648 B.  Bounce Wb [256][36]bf16 reuses base.
    __shared__ __align__(16) char sm[27648];
    __hip_bfloat16* As = (__hip_bfloat16*)sm;
    float* redS  = (float*)(sm + 16896);
    float* redQ  = (float*)(sm + 21120);
    float* red2S = (float*)(sm + 25344);
    float* red2Q = (float*)(sm + 26368);
    float* muS   = (float*)(sm + 27392);
    float* rsS   = (float*)(sm + 27520);

    int flat = blockIdx.x;           // 0..4095
    int xcd = flat & 7;
    int s = flat >> 3;               // 0..511
    int chalf = s & 1;
    int ph = (s >> 1) & 1;
    int hb = (s >> 2) & 7;
    int b  = s >> 5;                 // 0..15
    int h  = xcd * 8 + hb;
    int s0 = h * 64 + ph * 32;

    int tid = threadIdx.x;
    int x = tid & 7;                 // pos-quad: positions x*4..x*4+3
    int cg = tid >> 3;               // 0..31 channel-pair group

    // ---- stage A + LN partials ----
    const float* fb = f + (size_t)b * Cc * HW + s0 + x * 4;
    unsigned* Asu = (unsigned*)As;

    float lsum[4] = {0.f, 0.f, 0.f, 0.f};
    float lsq[4]  = {0.f, 0.f, 0.f, 0.f};
#pragma unroll
    for (int i = 0; i < 4; ++i) {
        int cp = i * 32 + cg;        // channel pair 0..127
        float4 v0 = *(const float4*)&fb[(size_t)(cp * 2) * HW];
        float4 v1 = *(const float4*)&fb[(size_t)(cp * 2 + 1) * HW];
        float a0[4] = {v0.x, v0.y, v0.z, v0.w};
        float a1[4] = {v1.x, v1.y, v1.z, v1.w};
#pragma unroll
        for (int j = 0; j < 4; ++j) {
            lsum[j] += a0[j] + a1[j];
            lsq[j]  += a0[j] * a0[j] + a1[j] * a1[j];
            unsigned pk = ((unsigned)__bfloat16_as_ushort(__float2bfloat16(a1[j])) << 16)
                        |  (unsigned)__bfloat16_as_ushort(__float2bfloat16(a0[j]));
            Asu[(size_t)(x * 4 + j) * (XPAD / 2) + cp] = pk;   // [pos][k-pair]
        }
    }
#pragma unroll
    for (int j = 0; j < 4; ++j) {
        redS[cg * 33 + x * 4 + j] = lsum[j];
        redQ[cg * 33 + x * 4 + j] = lsq[j];
    }

    // ---- B prefetch depth-2 + epilogue scalars (independent of LDS) ----
    int lane = tid & 63, wave = tid >> 6;      // 4 waves
    int col = lane & 15, quad = lane >> 4;
    int c0w = chalf * 256 + wave * 64;         // wave's 64 out-channels
    const __hip_bfloat16* Bp = W1g_b + (size_t)(c0w + col) * Cc + quad * 8;
    short8 B0[4], B1[4];
#pragma unroll
    for (int j = 0; j < 4; ++j) {
        B0[j] = *(const short8*)(Bp + (size_t)j * 16 * Cc);
        B1[j] = *(const short8*)(Bp + (size_t)j * 16 * Cc + 32);
    }
    float ws4[4], bi4[4];
#pragma unroll
    for (int j = 0; j < 4; ++j) {
        int c = c0w + j * 16 + col;
        ws4[j] = wsum[c];
        bi4[j] = bias1[c];
    }

    __syncthreads();                 // As + partials ready

    // stats reduce stage A: all 256 threads
    {
        int pos = tid & 31, g8 = tid >> 5;     // 8 groups x 4 cg each
        float ss = 0.f, qq = 0.f;
#pragma unroll
        for (int k = 0; k < 4; ++k) {
            ss += redS[(g8 * 4 + k) * 33 + pos];
            qq += redQ[(g8 * 4 + k) * 33 + pos];
        }
        red2S[g8 * 32 + pos] = ss;
        red2Q[g8 * 32 + pos] = qq;
    }
    __syncthreads();
    if (tid < 32) {
        float ss = 0.f, qq = 0.f;
#pragma unroll
        for (int g = 0; g < 8; ++g) { ss += red2S[g * 32 + tid]; qq += red2Q[g * 32 + tid]; }
        float m = ss * (1.0f / 256.0f);
        muS[tid] = m;
        rsS[tid] = rsqrtf(qq * (1.0f / 256.0f) - m * m + EPSc);
    }

    // ---- barrier-free K-loop (K=256, BK=32), depth-2 B prefetch ----
    floatx4 acc[2][4];
#pragma unroll
    for (int i = 0; i < 2; ++i)
#pragma unroll
        for (int j = 0; j < 4; ++j)
            acc[i][j] = (floatx4){0.f, 0.f, 0.f, 0.f};

#pragma unroll
    for (int ks = 0; ks < 8; ++ks) {
        int k0 = ks * 32;
        short8 af[2];
#pragma unroll
        for (int i = 0; i < 2; ++i)
            af[i] = *(const short8*)&As[(size_t)(i * 16 + col) * XPAD + k0 + quad * 8];
        __builtin_amdgcn_s_setprio(1);
#pragma unroll
        for (int i = 0; i < 2; ++i)
#pragma unroll
            for (int j = 0; j < 4; ++j)
                acc[i][j] = __builtin_amdgcn_mfma_f32_16x16x32_bf16(
                    af[i], (ks & 1) ? B1[j] : B0[j], acc[i][j], 0, 0, 0);
        __builtin_amdgcn_s_setprio(0);
        if (ks + 2 < 8) {
#pragma unroll
            for (int j = 0; j < 4; ++j) {
                short8 v = *(const short8*)(Bp + (size_t)j * 16 * Cc + k0 + 64);
                if (ks & 1) B1[j] = v; else B0[j] = v;
            }
        }
    }

    // ---- epilogue: affine -> Wb bounce -> coalesced 64B stores ----
    __syncthreads();                 // everyone done reading As
    __hip_bfloat16* Wb = (__hip_bfloat16*)sm;   // [256][36] bf16 = 18,432 B
#pragma unroll
    for (int i = 0; i < 2; ++i) {
        int pl = i * 16 + quad * 4;
        float4 mu4 = *(const float4*)&muS[pl];
        float4 rs4 = *(const float4*)&rsS[pl];
        float mu_[4] = {mu4.x, mu4.y, mu4.z, mu4.w};
        float rs_[4] = {rs4.x, rs4.y, rs4.z, rs4.w};
#pragma unroll
        for (int j = 0; j < 4; ++j) {
            int cl = wave * 64 + j * 16 + col;          // block-local out-ch
            __hip_bfloat16 v4[4];
#pragma unroll
            for (int r = 0; r < 4; ++r) {
                float v = (acc[i][j][r] - mu_[r] * ws4[j]) * rs_[r] + bi4[j];
                v4[r] = __float2bfloat16(v);
            }
            *(uint2*)&Wb[(size_t)cl * 36 + pl] = *(const uint2*)v4;
        }
    }
    __syncthreads();

    __hip_bfloat16* f5b = f5 + ((size_t)b * C2 + chalf * 256) * HW + s0;
    int rr = tid >> 3;               // 0..31 rows per pass
    int rc = tid & 7;                // uint2 column (8 x 8B = 64B per row)
#pragma unroll
    for (int pass = 0; pass < 8; ++pass) {
        int cl = pass * 32 + rr;
        uint2 v = *(const uint2*)&Wb[(size_t)cl * 36 + rc * 4];
        *(uint2*)&f5b[(size_t)cl * HW + rc * 4] = v;
    }
}

// ---------------------------------------------------------------------------
// Kernel 3: fused tail. This round: exact-erf gating replaced by tanh-form
// GELU reduced to v^2*(1 - rcp(exp(2u)+1)) — 8 VALU ops vs ~30 for erff.
// ---------------------------------------------------------------------------
#define TPITCH 520

__device__ inline float gate_gelu(float v) {
    // gelu_tanh(v)*v  (max |err| vs exact-erf form ~3e-4 per element)
    float t = v * v;
    float q = fmaf(0.0356774081f, t, 0.7978845608f);   // 0.79788456*(1+0.044715 v^2)
    float u = v * q;
    float e = __expf(2.0f * u);
    float r = __builtin_amdgcn_rcpf(e + 1.0f);
    return t - t * r;                                   // v^2 * e/(e+1)
}

#define P0_LOAD(dst, itc) do {                                               \
    int kk_ = (itc) * 128 + kb;                                              \
    _Pragma("unroll")                                                        \
    for (int dy_ = 0; dy_ < 3; ++dy_) {                                      \
        int hh_ = h + dy_ - 1;                                               \
        if ((unsigned)hh_ < Hh) {                                            \
            const __hip_bfloat16* row_ = f5b + (size_t)kk_ * HW + hh_ * Ww + w16; \
            dst[dy_][0] = *(const uint4*)&row_[0];                           \
            dst[dy_][1] = *(const uint4*)&row_[8];                           \
        } else {                                                             \
            dst[dy_][0] = make_uint4(0, 0, 0, 0);                            \
            dst[dy_][1] = make_uint4(0, 0, 0, 0);                            \
        }                                                                    \
    } } while (0)

__global__ __launch_bounds__(512, 4)
void fused_tail(const __hip_bfloat16* __restrict__ f5,
                const float* __restrict__ w_dw_p,
                const __hip_bfloat16* __restrict__ w_pw_b,
                const __hip_bfloat16* __restrict__ w_final_b,
                const float* __restrict__ f,
                float* __restrict__ out) {
    // union: tT [64][520] bf16 (66,560 B) for phases 0-2;
    //        Lf [256][68] f32 (69,632 B) for the out-bounce epilogue.
    __shared__ __align__(16) char smem[69632];
    __hip_bfloat16* tT = (__hip_bfloat16*)smem;
    float* Lf = (float*)smem;

    int flat = blockIdx.x;         // 0..1023
    int xcd = flat & 7;
    int slot = flat >> 3;          // 0..127
    int hb = slot & 7;
    int b  = slot >> 3;            // 0..15
    int h  = xcd * 8 + hb;

    int tid = threadIdx.x;
    int lane = tid & 63;
    int wave = tid >> 6;           // 0..7
    int col = lane & 15;
    int quad = lane >> 4;

    // ---- phase 0: depthwise 3x3 -> tT[pos][ch] (bf16, swizzled), depth-2 ----
    const __hip_bfloat16* f5b = f5 + (size_t)b * C2 * HW;
    int t4 = tid & 3;
    int kb = tid >> 2;             // 0..127
    int w16 = t4 * 16;

    uint4 bA[3][2], bB[3][2];
    P0_LOAD(bA, 0);
    P0_LOAD(bB, 1);

#pragma unroll
    for (int it = 0; it < 4; ++it) {
        int k = it * 128 + kb;
        const float4* wd4 = (const float4*)(w_dw_p + (size_t)k * 12);
        float4 wa = wd4[0], wb = wd4[1], wc2 = wd4[2];
        float wreg[9] = {wa.x, wa.y, wa.z, wa.w, wb.x, wb.y, wb.z, wb.w, wc2.x};
        float acc16[16] = {};
#pragma unroll
        for (int dy = 0; dy < 3; ++dy) {
            const __hip_bfloat16* pv =
                (const __hip_bfloat16*)((it & 1) ? &bB[dy][0] : &bA[dy][0]);
            float cv[16];
#pragma unroll
            for (int j = 0; j < 16; ++j) cv[j] = __bfloat162float(pv[j]);
            float l_in = __shfl_up(cv[15], 1);
            float r_in = __shfl_down(cv[0], 1);
            if (t4 == 0) l_in = 0.f;     // w = -1 -> zero pad
            if (t4 == 3) r_in = 0.f;     // w = 64 -> zero pad
            float win[18];
            win[0] = l_in;
#pragma unroll
            for (int j = 0; j < 16; ++j) win[j + 1] = cv[j];
            win[17] = r_in;
#pragma unroll
            for (int j = 0; j < 16; ++j)
                acc16[j] += wreg[dy * 3 + 0] * win[j] +
                            wreg[dy * 3 + 1] * win[j + 1] +
                            wreg[dy * 3 + 2] * win[j + 2];
        }
        if (it + 2 < 4) {
            if (it & 1) { P0_LOAD(bB, it + 2); } else { P0_LOAD(bA, it + 2); }
        }
        // swizzled store: row = w16+j (row>>4 == t4), element k ^ (t4<<4)
        int ksw = k ^ (t4 << 4);
#pragma unroll
        for (int j = 0; j < 16; ++j)
            tT[(size_t)(w16 + j) * TPITCH + ksw] = __float2bfloat16(acc16[j]);
    }

    // ---- phase 1: g = w_pw @ t; wave = 64 out x 64 pos, depth-2 A prefetch ----
    int wm0 = wave * 64;
    const __hip_bfloat16* Ap = w_pw_b + (size_t)(wm0 + col) * C2 + quad * 8;
    short8 A0[4], A1[4];
#pragma unroll
    for (int mt = 0; mt < 4; ++mt)
        A0[mt] = *(const short8*)(Ap + (size_t)mt * 16 * C2);

    __syncthreads();   // phase 0 done

#pragma unroll
    for (int mt = 0; mt < 4; ++mt)
        A1[mt] = *(const short8*)(Ap + (size_t)mt * 16 * C2 + 32);

    floatx4 acc[4][4];
#pragma unroll
    for (int mt = 0; mt < 4; ++mt)
#pragma unroll
        for (int nt = 0; nt < 4; ++nt)
            acc[mt][nt] = (floatx4){0.f, 0.f, 0.f, 0.f};

#pragma unroll
    for (int ks = 0; ks < 16; ++ks) {
        int k0 = ks * 32;
        short8 bfr[4];
#pragma unroll
        for (int nt = 0; nt < 4; ++nt)
            bfr[nt] = *(const short8*)&tT[(size_t)(nt * 16 + col) * TPITCH +
                                          ((k0 + quad * 8) ^ (nt << 4))];
        __builtin_amdgcn_s_setprio(1);
#pragma unroll
        for (int mt = 0; mt < 4; ++mt)
#pragma unroll
            for (int nt = 0; nt < 4; ++nt)
                acc[mt][nt] = __builtin_amdgcn_mfma_f32_16x16x32_bf16(
                    (ks & 1) ? A1[mt] : A0[mt], bfr[nt], acc[mt][nt], 0, 0, 0);
        __builtin_amdgcn_s_setprio(0);
        if (ks + 2 < 16) {
#pragma unroll
            for (int mt = 0; mt < 4; ++mt) {
                short8 v = *(const short8*)(Ap + (size_t)mt * 16 * C2 + k0 + 64);
                if (ks & 1) A1[mt] = v; else A0[mt] = v;
            }
        }
    }
    __syncthreads();   // everyone done reading tT (as t)

    // ---- gating: f7 = gelu(g)*g -> back into tT (same swizzle, key = nt) ----
#pragma unroll
    for (int mt = 0; mt < 4; ++mt)
#pragma unroll
        for (int nt = 0; nt < 4; ++nt) {
            __hip_bfloat16 v4[4];
#pragma unroll
            for (int r = 0; r < 4; ++r)
                v4[r] = __float2bfloat16(gate_gelu(acc[mt][nt][r]));
            *(uint2*)&tT[(size_t)(nt * 16 + col) * TPITCH +
                         ((wm0 + mt * 16 + quad * 4) ^ (nt << 4))] = *(const uint2*)v4;
        }

    // ---- phase 2: f8 = w_final @ f7; wave = 32 out x 64 pos; depth-2 ----
    int wm2 = wave * 32;
    const __hip_bfloat16* Af = w_final_b + (size_t)(wm2 + col) * C2 + quad * 8;
    short8 C0[2], C1[2];
#pragma unroll
    for (int mt = 0; mt < 2; ++mt)
        C0[mt] = *(const short8*)(Af + (size_t)mt * 16 * C2);

    __syncthreads();   // f7 fully written

#pragma unroll
    for (int mt = 0; mt < 2; ++mt)
        C1[mt] = *(const short8*)(Af + (size_t)mt * 16 * C2 + 32);

    floatx4 acc2[2][4];
#pragma unroll
    for (int mt = 0; mt < 2; ++mt)
#pragma unroll
        for (int nt = 0; nt < 4; ++nt)
            acc2[mt][nt] = (floatx4){0.f, 0.f, 0.f, 0.f};

#pragma unroll
    for (int ks = 0; ks < 16; ++ks) {
        int k0 = ks * 32;
        short8 bfr[4];
#pragma unroll
        for (int nt = 0; nt < 4; ++nt)
            bfr[nt] = *(const short8*)&tT[(size_t)(nt * 16 + col) * TPITCH +
                                          ((k0 + quad * 8) ^ (nt << 4))];
        __builtin_amdgcn_s_setprio(1);
#pragma unroll
        for (int mt = 0; mt < 2; ++mt)
#pragma unroll
            for (int nt = 0; nt < 4; ++nt)
                acc2[mt][nt] = __builtin_amdgcn_mfma_f32_16x16x32_bf16(
                    (ks & 1) ? C1[mt] : C0[mt], bfr[nt], acc2[mt][nt], 0, 0, 0);
        __builtin_amdgcn_s_setprio(0);
        if (ks + 2 < 16) {
#pragma unroll
            for (int mt = 0; mt < 2; ++mt) {
                short8 v = *(const short8*)(Af + (size_t)mt * 16 * C2 + k0 + 64);
                if (ks & 1) C1[mt] = v; else C0[mt] = v;
            }
        }
    }

    // ---- epilogue: f8 -> LDS (f32, pitch 68) -> coalesced out = f + f8 ----
    __syncthreads();   // all waves done reading tT (as f7)
#pragma unroll
    for (int mt = 0; mt < 2; ++mt)
#pragma unroll
        for (int nt = 0; nt < 4; ++nt)
#pragma unroll
            for (int r = 0; r < 4; ++r) {
                int m = wm2 + mt * 16 + quad * 4 + r;
                int n = nt * 16 + col;
                Lf[(size_t)m * 68 + n] = acc2[mt][nt][r];
            }
    __syncthreads();

    const float* fb = f + (size_t)b * Cc * HW + h * Ww;
    float* ob = out + (size_t)b * Cc * HW + h * Ww;
    int pr = tid >> 4;      // 0..31 : channel row within pass
    int pc = tid & 15;      // float4 column (16 x 16B = 256B per row)
#pragma unroll
    for (int pass = 0; pass < 8; ++pass) {
        int m = pass * 32 + pr;
        float4 v = *(const float4*)&Lf[(size_t)m * 68 + pc * 4];
        float4 rr4 = *(const float4*)&fb[(size_t)m * HW + pc * 4];
        v.x += rr4.x; v.y += rr4.y; v.z += rr4.z; v.w += rr4.w;
        *(float4*)&ob[(size_t)m * HW + pc * 4] = v;
    }
}

// ---------------------------------------------------------------------------
extern "C" void kernel_launch(void* const* d_in, const int* in_sizes, int n_in,
                              void* d_out, int out_size, void* d_ws, size_t ws_size,
                              hipStream_t stream) {
    const float* f         = (const float*)d_in[0];
    const float* ln_gamma  = (const float*)d_in[1];
    const float* ln_beta   = (const float*)d_in[2];
    const float* w_expand  = (const float*)d_in[3];
    const float* freq_real = (const float*)d_in[4];
    // d_in[5] = freq_imag: provably unused (Re((r+ij)*x) for real x = r*x)
    const float* w_poly    = (const float*)d_in[6];
    const float* w_dw      = (const float*)d_in[7];
    const float* w_pw      = (const float*)d_in[8];
    const float* w_final   = (const float*)d_in[9];
    float* out = (float*)d_out;

    // workspace layout
    char* p = (char*)d_ws;
    __hip_bfloat16* f5   = (__hip_bfloat16*)p;  p += (size_t)C2 * Pp * 2;   // 64 MiB
    __hip_bfloat16* W1g_b = (__hip_bfloat16*)p; p += (size_t)C2 * Cc * 2;
    float* bias1 = (float*)p;                   p += (size_t)C2 * 4;
    float* wsum  = (float*)p;                   p += (size_t)C2 * 4;
    __hip_bfloat16* w_pw_b    = (__hip_bfloat16*)p;  p += (size_t)C2 * C2 * 2;
    __hip_bfloat16* w_final_b = (__hip_bfloat16*)p;  p += (size_t)Cc * C2 * 2;
    float* w_dw_p = (float*)p;                  p += (size_t)C2 * 12 * 4;

    // blocks 0..511: combine; 512..715: prep (98304+6144 items / 512)
    weights_all<<<dim3(716), dim3(512), 0, stream>>>(
        w_expand, freq_real, w_poly, ln_gamma, ln_beta,
        w_pw, w_final, w_dw,
        W1g_b, bias1, wsum, w_pw_b, w_final_b, w_dw_p);

    gemm1h<<<dim3(4096), dim3(256), 0, stream>>>(
        f, W1g_b, bias1, wsum, f5);

    fused_tail<<<dim3(1024), dim3(512), 0, stream>>>(
        f5, w_dw_p, w_pw_b, w_final_b, f, out);
}

// Round 7
// 323.439 us; speedup vs baseline: 1.0521x; 1.0521x over previous
//
#include <hip/hip_runtime.h>
#include <hip/hip_bf16.h>
#include <math.h>

// Problem constants
#define Bn 16
#define Cc 256
#define Hh 64
#define Ww 64
#define HW 4096
#define C2 512
#define Pp 65536          // Bn*HW
#define EPSc 1e-5f

typedef __attribute__((ext_vector_type(8))) short short8;
typedef __attribute__((ext_vector_type(4))) float floatx4;

// ---------------------------------------------------------------------------
// Kernel 0 (merged): blocks 0..511 combine weights (split-K);
// blocks 512.. convert w_pw/w_final to bf16 and pad w_dw.
// ---------------------------------------------------------------------------
__device__ inline void cvt4(const float* __restrict__ a,
                            __hip_bfloat16* __restrict__ o, int q) {
    float4 v = *(const float4*)&a[q * 4];
    __hip_bfloat16 r[4];
    r[0] = __float2bfloat16(v.x);
    r[1] = __float2bfloat16(v.y);
    r[2] = __float2bfloat16(v.z);
    r[3] = __float2bfloat16(v.w);
    *(uint2*)&o[q * 4] = *(const uint2*)r;
}

__global__ __launch_bounds__(512)
void weights_all(const float* __restrict__ w_expand,
                 const float* __restrict__ freq_real,
                 const float* __restrict__ w_poly,
                 const float* __restrict__ gamma,
                 const float* __restrict__ beta,
                 const float* __restrict__ w_pw,
                 const float* __restrict__ w_final,
                 const float* __restrict__ w_dw,
                 __hip_bfloat16* __restrict__ W1g_b,
                 float* __restrict__ bias1,
                 float* __restrict__ wsum,
                 __hip_bfloat16* __restrict__ w_pw_b,
                 __hip_bfloat16* __restrict__ w_final_b,
                 float* __restrict__ w_dw_p) {
    int tid = threadIdx.x;
    if (blockIdx.x >= 512) {
        int i = (blockIdx.x - 512) * 512 + tid;
        if (i < 65536) {
            cvt4(w_pw, w_pw_b, i);
        } else if (i < 98304) {
            cvt4(w_final, w_final_b, i - 65536);
        } else {
            int j = i - 98304;
            if (j < C2 * 12) {
                int k = j / 12, l = j - k * 12;
                w_dw_p[j] = (l < 9) ? w_dw[k * 9 + l] : 0.f;
            }
        }
        return;
    }
    int o = blockIdx.x;
    int c = tid & 255;
    int kh = tid >> 8;           // 0/1: K-half
    float acc = 0.f;
    const float* wp = w_poly + (size_t)o * C2 + kh * 256;
    const float* fr = freq_real + kh * 256;
    const float* we = w_expand + (size_t)(kh * 256) * Cc + c;
    for (int m = 0; m < 256; ++m) {
        acc += wp[m] * fr[m] * we[(size_t)m * Cc];
    }
    __shared__ float part[512];
    __shared__ float redB[256];
    __shared__ float redG[256];
    part[tid] = acc;
    __syncthreads();
    if (tid < 256) {
        float a = part[tid] + part[tid + 256];
        float wg = a * gamma[c];
        W1g_b[(size_t)o * Cc + c] = __float2bfloat16(wg);
        redB[c] = a * beta[c];
        redG[c] = wg;
    }
    __syncthreads();
    for (int s = 128; s > 0; s >>= 1) {
        if (tid < s) { redB[tid] += redB[tid + s]; redG[tid] += redG[tid + s]; }
        __syncthreads();
    }
    if (tid == 0) { bias1[o] = redB[0]; wsum[o] = redG[0]; }
}

// ---------------------------------------------------------------------------
// Kernel 1: gemm1f — fused LN-stats + GEMM1, one block per (b,h) row.
// 1024 blocks x 512 thr. This round: LDS diet (stats partials via wave
// shfl_xor reduce, 16.5KB -> 4KB) => 38.4KB total => 4 blocks/CU (32 waves,
// was 24). Stage A from f (fp32->bf16) + LN partials; barrier-free K-loop
// with depth-2 B register prefetch; affine epilogue -> LDS bounce ->
// 128B-coalesced f5 stores.
// ---------------------------------------------------------------------------
#define XPAD 264   // LDS A-row pitch in bf16 (528 B = 66*8, 16B-aligned)

__global__ __launch_bounds__(512, 4)
void gemm1f(const float* __restrict__ f,
            const __hip_bfloat16* __restrict__ W1g_b,
            const float* __restrict__ bias1,
            const float* __restrict__ wsum,
            __hip_bfloat16* __restrict__ f5) {
    // carve: As 33792 | redW 4096 | muS 256 | rsS 256 = 38,400 B
    // epilogue bounce Wb [256][72] bf16 = 36,864 B reuses [0, 36864) —
    // does not touch muS/rsS at 37,888+.
    __shared__ __align__(16) char sm[38400];
    __hip_bfloat16* As = (__hip_bfloat16*)sm;
    float* redW = (float*)(sm + 33792);      // [2][8 waves][64 pos]
    float* muS  = (float*)(sm + 37888);
    float* rsS  = (float*)(sm + 38144);

    int flat = blockIdx.x;       // 0..1023
    int b = flat >> 6;
    int h = flat & 63;
    int s0 = h * 64;

    int tid = threadIdx.x;
    int x = tid & 15;            // n-quad: positions x*4..x*4+3
    int cg = tid >> 4;           // 0..31 channel-pair group

    // ---- stage A + LN partials ----
    const float* fb = f + (size_t)b * Cc * HW + s0 + x * 4;
    unsigned* Asu = (unsigned*)&As[0];

    float lsum[4] = {0.f, 0.f, 0.f, 0.f};
    float lsq[4]  = {0.f, 0.f, 0.f, 0.f};
#pragma unroll
    for (int i = 0; i < 4; ++i) {
        int cp = i * 32 + cg;    // channel pair 0..127 -> channels 2cp, 2cp+1
        float4 v0 = *(const float4*)&fb[(size_t)(cp * 2) * HW];
        float4 v1 = *(const float4*)&fb[(size_t)(cp * 2 + 1) * HW];
        float a0[4] = {v0.x, v0.y, v0.z, v0.w};
        float a1[4] = {v1.x, v1.y, v1.z, v1.w};
#pragma unroll
        for (int j = 0; j < 4; ++j) {
            lsum[j] += a0[j] + a1[j];
            lsq[j]  += a0[j] * a0[j] + a1[j] * a1[j];
            unsigned pk = ((unsigned)__bfloat16_as_ushort(__float2bfloat16(a1[j])) << 16)
                        |  (unsigned)__bfloat16_as_ushort(__float2bfloat16(a0[j]));
            Asu[(size_t)(x * 4 + j) * (XPAD / 2) + cp] = pk;   // [n][k-pair]
        }
    }

    int lane = tid & 63, wave = tid >> 6;     // 8 waves
    int col = lane & 15, quad = lane >> 4;

    // wave-level reduce over the 4 cg's sharing this col (quad axis)
#pragma unroll
    for (int j = 0; j < 4; ++j) {
        lsum[j] += __shfl_xor(lsum[j], 16);
        lsum[j] += __shfl_xor(lsum[j], 32);
        lsq[j]  += __shfl_xor(lsq[j], 16);
        lsq[j]  += __shfl_xor(lsq[j], 32);
    }
    if (quad == 0) {
#pragma unroll
        for (int j = 0; j < 4; ++j) {
            redW[wave * 64 + col * 4 + j]       = lsum[j];
            redW[512 + wave * 64 + col * 4 + j] = lsq[j];
        }
    }

    // ---- B prefetch depth-2 + epilogue scalars (independent of LDS) ----
    int c0w = wave * 64;                      // wave owns c0w..c0w+63 x all 64 pos
    const __hip_bfloat16* Bp = W1g_b + (size_t)(c0w + col) * Cc + quad * 8;
    short8 B0[4], B1[4];
#pragma unroll
    for (int j = 0; j < 4; ++j) {
        B0[j] = *(const short8*)(Bp + (size_t)j * 16 * Cc);
        B1[j] = *(const short8*)(Bp + (size_t)j * 16 * Cc + 32);
    }
    float ws4[4], bi4[4];
#pragma unroll
    for (int j = 0; j < 4; ++j) {
        int c = c0w + j * 16 + col;
        ws4[j] = wsum[c];
        bi4[j] = bias1[c];
    }

    __syncthreads();
    if (tid < 64) {
        float s = 0.f, q = 0.f;
#pragma unroll
        for (int g = 0; g < 8; ++g) {
            s += redW[g * 64 + tid];
            q += redW[512 + g * 64 + tid];
        }
        float m = s * (1.0f / 256.0f);
        muS[tid] = m;
        rsS[tid] = rsqrtf(q * (1.0f / 256.0f) - m * m + EPSc);
    }
    __syncthreads();

    // ---- barrier-free K-loop (K=256, BK=32), depth-2 B prefetch ----
    floatx4 acc[4][4];
#pragma unroll
    for (int i = 0; i < 4; ++i)
#pragma unroll
        for (int j = 0; j < 4; ++j)
            acc[i][j] = (floatx4){0.f, 0.f, 0.f, 0.f};

#pragma unroll
    for (int ks = 0; ks < 8; ++ks) {
        int k0 = ks * 32;
        short8 af[4];
#pragma unroll
        for (int i = 0; i < 4; ++i)
            af[i] = *(const short8*)&As[(size_t)(i * 16 + col) * XPAD + k0 + quad * 8];
        __builtin_amdgcn_s_setprio(1);
#pragma unroll
        for (int i = 0; i < 4; ++i)
#pragma unroll
            for (int j = 0; j < 4; ++j)
                acc[i][j] = __builtin_amdgcn_mfma_f32_16x16x32_bf16(
                    af[i], (ks & 1) ? B1[j] : B0[j], acc[i][j], 0, 0, 0);
        __builtin_amdgcn_s_setprio(0);
        if (ks + 2 < 8) {
#pragma unroll
            for (int j = 0; j < 4; ++j) {
                short8 v = *(const short8*)(Bp + (size_t)j * 16 * Cc + k0 + 64);
                if (ks & 1) B1[j] = v; else B0[j] = v;
            }
        }
    }

    // ---- epilogue: affine -> LDS bounce -> fully-coalesced 128B stores ----
    __syncthreads();             // all waves done reading As
    __hip_bfloat16* Wb = (__hip_bfloat16*)sm;   // [256][72] bf16 = 36,864 B
    __hip_bfloat16* f5b = f5 + (size_t)b * C2 * HW + s0;
    int rr = tid >> 3;           // 0..63 : channel row within pass
    int rc = tid & 7;            // uint4 column
#pragma unroll
    for (int chunk = 0; chunk < 2; ++chunk) {
        if ((wave >> 2) == chunk) {
            int cbase = c0w & 255;
#pragma unroll
            for (int i = 0; i < 4; ++i) {
                int pl = i * 16 + quad * 4;
                float4 mu4 = *(const float4*)&muS[pl];
                float4 rs4 = *(const float4*)&rsS[pl];
                float mu_[4] = {mu4.x, mu4.y, mu4.z, mu4.w};
                float rs_[4] = {rs4.x, rs4.y, rs4.z, rs4.w};
#pragma unroll
                for (int j = 0; j < 4; ++j) {
                    int cl = cbase + j * 16 + col;
                    __hip_bfloat16 v4[4];
#pragma unroll
                    for (int r = 0; r < 4; ++r) {
                        float v = (acc[i][j][r] - mu_[r] * ws4[j]) * rs_[r] + bi4[j];
                        v4[r] = __float2bfloat16(v);
                    }
                    *(uint2*)&Wb[(size_t)cl * 72 + pl] = *(const uint2*)v4;
                }
            }
        }
        __syncthreads();
#pragma unroll
        for (int pass = 0; pass < 4; ++pass) {
            int cl = pass * 64 + rr;
            uint4 v = *(const uint4*)&Wb[(size_t)cl * 72 + rc * 8];
            *(uint4*)&f5b[(size_t)(chunk * 256 + cl) * HW + rc * 8] = v;
        }
        if (chunk == 0) __syncthreads();
    }
}

// ---------------------------------------------------------------------------
// Kernel 3: fused tail (unchanged from R6: tT swizzle, LDS-bounce epilogues,
// depth-2 prefetch, setprio, fast tanh-form GELU gating).
// ---------------------------------------------------------------------------
#define TPITCH 520

__device__ inline float gate_gelu(float v) {
    // gelu_tanh(v)*v  (max |err| vs exact-erf form ~3e-4 per element)
    float t = v * v;
    float q = fmaf(0.0356774081f, t, 0.7978845608f);   // 0.79788456*(1+0.044715 v^2)
    float u = v * q;
    float e = __expf(2.0f * u);
    float r = __builtin_amdgcn_rcpf(e + 1.0f);
    return t - t * r;                                   // v^2 * e/(e+1)
}

#define P0_LOAD(dst, itc) do {                                               \
    int kk_ = (itc) * 128 + kb;                                              \
    _Pragma("unroll")                                                        \
    for (int dy_ = 0; dy_ < 3; ++dy_) {                                      \
        int hh_ = h + dy_ - 1;                                               \
        if ((unsigned)hh_ < Hh) {                                            \
            const __hip_bfloat16* row_ = f5b + (size_t)kk_ * HW + hh_ * Ww + w16; \
            dst[dy_][0] = *(const uint4*)&row_[0];                           \
            dst[dy_][1] = *(const uint4*)&row_[8];                           \
        } else {                                                             \
            dst[dy_][0] = make_uint4(0, 0, 0, 0);                            \
            dst[dy_][1] = make_uint4(0, 0, 0, 0);                            \
        }                                                                    \
    } } while (0)

__global__ __launch_bounds__(512, 4)
void fused_tail(const __hip_bfloat16* __restrict__ f5,
                const float* __restrict__ w_dw_p,
                const __hip_bfloat16* __restrict__ w_pw_b,
                const __hip_bfloat16* __restrict__ w_final_b,
                const float* __restrict__ f,
                float* __restrict__ out) {
    // union: tT [64][520] bf16 (66,560 B) for phases 0-2;
    //        Lf [256][68] f32 (69,632 B) for the out-bounce epilogue.
    __shared__ __align__(16) char smem[69632];
    __hip_bfloat16* tT = (__hip_bfloat16*)smem;
    float* Lf = (float*)smem;

    int flat = blockIdx.x;         // 0..1023
    int xcd = flat & 7;
    int slot = flat >> 3;          // 0..127
    int hb = slot & 7;
    int b  = slot >> 3;            // 0..15
    int h  = xcd * 8 + hb;

    int tid = threadIdx.x;
    int lane = tid & 63;
    int wave = tid >> 6;           // 0..7
    int col = lane & 15;
    int quad = lane >> 4;

    // ---- phase 0: depthwise 3x3 -> tT[pos][ch] (bf16, swizzled), depth-2 ----
    const __hip_bfloat16* f5b = f5 + (size_t)b * C2 * HW;
    int t4 = tid & 3;
    int kb = tid >> 2;             // 0..127
    int w16 = t4 * 16;

    uint4 bA[3][2], bB[3][2];
    P0_LOAD(bA, 0);
    P0_LOAD(bB, 1);

#pragma unroll
    for (int it = 0; it < 4; ++it) {
        int k = it * 128 + kb;
        const float4* wd4 = (const float4*)(w_dw_p + (size_t)k * 12);
        float4 wa = wd4[0], wb = wd4[1], wc2 = wd4[2];
        float wreg[9] = {wa.x, wa.y, wa.z, wa.w, wb.x, wb.y, wb.z, wb.w, wc2.x};
        float acc16[16] = {};
#pragma unroll
        for (int dy = 0; dy < 3; ++dy) {
            const __hip_bfloat16* pv =
                (const __hip_bfloat16*)((it & 1) ? &bB[dy][0] : &bA[dy][0]);
            float cv[16];
#pragma unroll
            for (int j = 0; j < 16; ++j) cv[j] = __bfloat162float(pv[j]);
            float l_in = __shfl_up(cv[15], 1);
            float r_in = __shfl_down(cv[0], 1);
            if (t4 == 0) l_in = 0.f;     // w = -1 -> zero pad
            if (t4 == 3) r_in = 0.f;     // w = 64 -> zero pad
            float win[18];
            win[0] = l_in;
#pragma unroll
            for (int j = 0; j < 16; ++j) win[j + 1] = cv[j];
            win[17] = r_in;
#pragma unroll
            for (int j = 0; j < 16; ++j)
                acc16[j] += wreg[dy * 3 + 0] * win[j] +
                            wreg[dy * 3 + 1] * win[j + 1] +
                            wreg[dy * 3 + 2] * win[j + 2];
        }
        if (it + 2 < 4) {
            if (it & 1) { P0_LOAD(bB, it + 2); } else { P0_LOAD(bA, it + 2); }
        }
        // swizzled store: row = w16+j (row>>4 == t4), element k ^ (t4<<4)
        int ksw = k ^ (t4 << 4);
#pragma unroll
        for (int j = 0; j < 16; ++j)
            tT[(size_t)(w16 + j) * TPITCH + ksw] = __float2bfloat16(acc16[j]);
    }

    // ---- phase 1: g = w_pw @ t; wave = 64 out x 64 pos, depth-2 A prefetch ----
    int wm0 = wave * 64;
    const __hip_bfloat16* Ap = w_pw_b + (size_t)(wm0 + col) * C2 + quad * 8;
    short8 A0[4], A1[4];
#pragma unroll
    for (int mt = 0; mt < 4; ++mt)
        A0[mt] = *(const short8*)(Ap + (size_t)mt * 16 * C2);

    __syncthreads();   // phase 0 done

#pragma unroll
    for (int mt = 0; mt < 4; ++mt)
        A1[mt] = *(const short8*)(Ap + (size_t)mt * 16 * C2 + 32);

    floatx4 acc[4][4];
#pragma unroll
    for (int mt = 0; mt < 4; ++mt)
#pragma unroll
        for (int nt = 0; nt < 4; ++nt)
            acc[mt][nt] = (floatx4){0.f, 0.f, 0.f, 0.f};

#pragma unroll
    for (int ks = 0; ks < 16; ++ks) {
        int k0 = ks * 32;
        short8 bfr[4];
#pragma unroll
        for (int nt = 0; nt < 4; ++nt)
            bfr[nt] = *(const short8*)&tT[(size_t)(nt * 16 + col) * TPITCH +
                                          ((k0 + quad * 8) ^ (nt << 4))];
        __builtin_amdgcn_s_setprio(1);
#pragma unroll
        for (int mt = 0; mt < 4; ++mt)
#pragma unroll
            for (int nt = 0; nt < 4; ++nt)
                acc[mt][nt] = __builtin_amdgcn_mfma_f32_16x16x32_bf16(
                    (ks & 1) ? A1[mt] : A0[mt], bfr[nt], acc[mt][nt], 0, 0, 0);
        __builtin_amdgcn_s_setprio(0);
        if (ks + 2 < 16) {
#pragma unroll
            for (int mt = 0; mt < 4; ++mt) {
                short8 v = *(const short8*)(Ap + (size_t)mt * 16 * C2 + k0 + 64);
                if (ks & 1) A1[mt] = v; else A0[mt] = v;
            }
        }
    }
    __syncthreads();   // everyone done reading tT (as t)

    // ---- gating: f7 = gelu(g)*g -> back into tT (same swizzle, key = nt) ----
#pragma unroll
    for (int mt = 0; mt < 4; ++mt)
#pragma unroll
        for (int nt = 0; nt < 4; ++nt) {
            __hip_bfloat16 v4[4];
#pragma unroll
            for (int r = 0; r < 4; ++r)
                v4[r] = __float2bfloat16(gate_gelu(acc[mt][nt][r]));
            *(uint2*)&tT[(size_t)(nt * 16 + col) * TPITCH +
                         ((wm0 + mt * 16 + quad * 4) ^ (nt << 4))] = *(const uint2*)v4;
        }

    // ---- phase 2: f8 = w_final @ f7; wave = 32 out x 64 pos; depth-2 ----
    int wm2 = wave * 32;
    const __hip_bfloat16* Af = w_final_b + (size_t)(wm2 + col) * C2 + quad * 8;
    short8 C0[2], C1[2];
#pragma unroll
    for (int mt = 0; mt < 2; ++mt)
        C0[mt] = *(const short8*)(Af + (size_t)mt * 16 * C2);

    __syncthreads();   // f7 fully written

#pragma unroll
    for (int mt = 0; mt < 2; ++mt)
        C1[mt] = *(const short8*)(Af + (size_t)mt * 16 * C2 + 32);

    floatx4 acc2[2][4];
#pragma unroll
    for (int mt = 0; mt < 2; ++mt)
#pragma unroll
        for (int nt = 0; nt < 4; ++nt)
            acc2[mt][nt] = (floatx4){0.f, 0.f, 0.f, 0.f};

#pragma unroll
    for (int ks = 0; ks < 16; ++ks) {
        int k0 = ks * 32;
        short8 bfr[4];
#pragma unroll
        for (int nt = 0; nt < 4; ++nt)
            bfr[nt] = *(const short8*)&tT[(size_t)(nt * 16 + col) * TPITCH +
                                          ((k0 + quad * 8) ^ (nt << 4))];
        __builtin_amdgcn_s_setprio(1);
#pragma unroll
        for (int mt = 0; mt < 2; ++mt)
#pragma unroll
            for (int nt = 0; nt < 4; ++nt)
                acc2[mt][nt] = __builtin_amdgcn_mfma_f32_16x16x32_bf16(
                    (ks & 1) ? C1[mt] : C0[mt], bfr[nt], acc2[mt][nt], 0, 0, 0);
        __builtin_amdgcn_s_setprio(0);
        if (ks + 2 < 16) {
#pragma unroll
            for (int mt = 0; mt < 2; ++mt) {
                short8 v = *(const short8*)(Af + (size_t)mt * 16 * C2 + k0 + 64);
                if (ks & 1) C1[mt] = v; else C0[mt] = v;
            }
        }
    }

    // ---- epilogue: f8 -> LDS (f32, pitch 68) -> coalesced out = f + f8 ----
    __syncthreads();   // all waves done reading tT (as f7)
#pragma unroll
    for (int mt = 0; mt < 2; ++mt)
#pragma unroll
        for (int nt = 0; nt < 4; ++nt)
#pragma unroll
            for (int r = 0; r < 4; ++r) {
                int m = wm2 + mt * 16 + quad * 4 + r;
                int n = nt * 16 + col;
                Lf[(size_t)m * 68 + n] = acc2[mt][nt][r];
            }
    __syncthreads();

    const float* fb = f + (size_t)b * Cc * HW + h * Ww;
    float* ob = out + (size_t)b * Cc * HW + h * Ww;
    int pr = tid >> 4;      // 0..31 : channel row within pass
    int pc = tid & 15;      // float4 column (16 x 16B = 256B per row)
#pragma unroll
    for (int pass = 0; pass < 8; ++pass) {
        int m = pass * 32 + pr;
        float4 v = *(const float4*)&Lf[(size_t)m * 68 + pc * 4];
        float4 rr4 = *(const float4*)&fb[(size_t)m * HW + pc * 4];
        v.x += rr4.x; v.y += rr4.y; v.z += rr4.z; v.w += rr4.w;
        *(float4*)&ob[(size_t)m * HW + pc * 4] = v;
    }
}

// ---------------------------------------------------------------------------
extern "C" void kernel_launch(void* const* d_in, const int* in_sizes, int n_in,
                              void* d_out, int out_size, void* d_ws, size_t ws_size,
                              hipStream_t stream) {
    const float* f         = (const float*)d_in[0];
    const float* ln_gamma  = (const float*)d_in[1];
    const float* ln_beta   = (const float*)d_in[2];
    const float* w_expand  = (const float*)d_in[3];
    const float* freq_real = (const float*)d_in[4];
    // d_in[5] = freq_imag: provably unused (Re((r+ij)*x) for real x = r*x)
    const float* w_poly    = (const float*)d_in[6];
    const float* w_dw      = (const float*)d_in[7];
    const float* w_pw      = (const float*)d_in[8];
    const float* w_final   = (const float*)d_in[9];
    float* out = (float*)d_out;

    // workspace layout
    char* p = (char*)d_ws;
    __hip_bfloat16* f5   = (__hip_bfloat16*)p;  p += (size_t)C2 * Pp * 2;   // 64 MiB
    __hip_bfloat16* W1g_b = (__hip_bfloat16*)p; p += (size_t)C2 * Cc * 2;
    float* bias1 = (float*)p;                   p += (size_t)C2 * 4;
    float* wsum  = (float*)p;                   p += (size_t)C2 * 4;
    __hip_bfloat16* w_pw_b    = (__hip_bfloat16*)p;  p += (size_t)C2 * C2 * 2;
    __hip_bfloat16* w_final_b = (__hip_bfloat16*)p;  p += (size_t)Cc * C2 * 2;
    float* w_dw_p = (float*)p;                  p += (size_t)C2 * 12 * 4;

    // blocks 0..511: combine; 512..715: prep (98304+6144 items / 512)
    weights_all<<<dim3(716), dim3(512), 0, stream>>>(
        w_expand, freq_real, w_poly, ln_gamma, ln_beta,
        w_pw, w_final, w_dw,
        W1g_b, bias1, wsum, w_pw_b, w_final_b, w_dw_p);

    gemm1f<<<dim3(1024), dim3(512), 0, stream>>>(
        f, W1g_b, bias1, wsum, f5);

    fused_tail<<<dim3(1024), dim3(512), 0, stream>>>(
        f5, w_dw_p, w_pw_b, w_final_b, f, out);
}